// Round 11
// baseline (4814.142 us; speedup 1.0000x reference)
//
#include <hip/hip_runtime.h>
#include <hip/hip_bf16.h>

#define IN_DIM 768
#define HID 128
#define NC 7
#define GSH 13        // src-group = src >> 13 (8192 rows = 2 MB of G)
#define MNODES 196    // nodes per persistent agg block

typedef __attribute__((ext_vector_type(8))) short bf16x8;
typedef __attribute__((ext_vector_type(4))) float f32x4;

__device__ __forceinline__ ushort f2bf(float f) {
  uint u = __float_as_uint(f);
  u += 0x7fffu + ((u >> 16) & 1u);
  return (ushort)(u >> 16);
}
__device__ __forceinline__ float lof(uint v) { return __uint_as_float(v << 16); }
__device__ __forceinline__ float hif(uint v) { return __uint_as_float(v & 0xffff0000u); }
__device__ __forceinline__ uint cvtpk(float lo, float hi) {
  uint r;
  asm("v_cvt_pk_bf16_f32 %0, %1, %2" : "=v"(r) : "v"(lo), "v"(hi));
  return r;
}

// ---------------- CSR build: group-major (g,dst) layout ----------------

// histogram per (src-group, dst); pos[e] = arrival order within (g,dst)
__global__ __launch_bounds__(256) void k_count2(const int* __restrict__ src,
                                                const int* __restrict__ dst,
                                                int* __restrict__ cnt2,
                                                int* __restrict__ pos, int E, int N) {
  int e0 = (blockIdx.x * 256 + threadIdx.x) * 4;
  if (e0 + 4 <= E) {
    int4 s4 = *(const int4*)&src[e0];
    int4 d4 = *(const int4*)&dst[e0];
    int4 p;
    p.x = atomicAdd(&cnt2[(s4.x >> GSH) * N + d4.x], 1);
    p.y = atomicAdd(&cnt2[(s4.y >> GSH) * N + d4.y], 1);
    p.z = atomicAdd(&cnt2[(s4.z >> GSH) * N + d4.z], 1);
    p.w = atomicAdd(&cnt2[(s4.w >> GSH) * N + d4.w], 1);
    *(int4*)&pos[e0] = p;
  } else {
    for (int e = e0; e < E; ++e)
      pos[e] = atomicAdd(&cnt2[(src[e] >> GSH) * N + dst[e]], 1);
  }
}

// degree (sum over groups) -> dinv
__global__ void k_deg(const int* __restrict__ cnt2, float* __restrict__ dinv,
                      int N, int NG) {
  int n = blockIdx.x * 256 + threadIdx.x;
  if (n >= N) return;
  int s = 0;
  for (int g = 0; g < NG; ++g) s += cnt2[(size_t)g * N + n];
  dinv[n] = rsqrtf((float)(s + 1));
}

// big scan over NPAD elements (16384 per block, 64 per thread)
__global__ void k_scanP2(const int* __restrict__ a, int* __restrict__ partials) {
  __shared__ int sm[256];
  int b = blockIdx.x, t = threadIdx.x;
  long base = (long)b * 16384 + t * 64;
  int s = 0;
  #pragma unroll
  for (int j = 0; j < 16; ++j) {
    int4 v = *(const int4*)&a[base + j * 4];
    s += v.x + v.y + v.z + v.w;
  }
  sm[t] = s;
  __syncthreads();
  for (int off = 128; off > 0; off >>= 1) {
    if (t < off) sm[t] += sm[t + off];
    __syncthreads();
  }
  if (t == 0) partials[b] = sm[0];
}

__global__ void k_scanC2(int* __restrict__ partials, int nch) {
  __shared__ int sm[128];
  int t = threadIdx.x;
  int v0 = (t < nch) ? partials[t] : 0;
  sm[t] = v0;
  __syncthreads();
  for (int off = 1; off < 128; off <<= 1) {
    int add = (t >= off) ? sm[t - off] : 0;
    __syncthreads();
    sm[t] += add;
    __syncthreads();
  }
  if (t < nch) partials[t] = sm[t] - v0;   // exclusive chunk offset
}

__global__ void k_scanF2(const int* __restrict__ a, const int* __restrict__ chunkoff,
                         int* __restrict__ out) {
  __shared__ int sm[256];
  int b = blockIdx.x, t = threadIdx.x;
  long base = (long)b * 16384 + t * 64;
  int4 arr[16];
  int s = 0;
  #pragma unroll
  for (int j = 0; j < 16; ++j) {
    arr[j] = *(const int4*)&a[base + j * 4];
    s += arr[j].x + arr[j].y + arr[j].z + arr[j].w;
  }
  sm[t] = s;
  __syncthreads();
  for (int off = 1; off < 256; off <<= 1) {
    int add = (t >= off) ? sm[t - off] : 0;
    __syncthreads();
    sm[t] += add;
    __syncthreads();
  }
  int run = chunkoff[b] + sm[t] - s;
  #pragma unroll
  for (int j = 0; j < 16; ++j) {
    int4 o;
    o.x = run; run += arr[j].x;
    o.y = run; run += arr[j].y;
    o.z = run; run += arr[j].z;
    o.w = run; run += arr[j].w;
    *(int4*)&out[base + j * 4] = o;
  }
}

// ---------------- weight convert/transpose (r6-proven) ----------------
__global__ void k_convW(const float* __restrict__ W, ushort* __restrict__ WT, int K) {
  int i = blockIdx.x * 256 + threadIdx.x;
  if (i >= K * HID) return;
  int k = i >> 7, c = i & 127;
  WT[c * K + k] = f2bf(W[i]);
}

// ---------------- mega bodies ----------------

// gemm1 body (r10-proven verbatim)
__device__ __forceinline__
void gemm1_body(ushort (*lB)[128 * 64],
                const float* __restrict__ A, const ushort* __restrict__ WT,
                const float* __restrict__ dinv, ushort* __restrict__ G,
                const int N, int b) {
  const int tid = threadIdx.x;
  const int lane = tid & 63;
  const int wid = tid >> 6;
  const int lr = lane & 15, lq = lane >> 4;
  const int rb = b * 128 + wid * 16;
  int ar0 = rb + lr;      if (ar0 > N - 1) ar0 = N - 1;
  int ar1 = rb + 64 + lr; if (ar1 > N - 1) ar1 = N - 1;
  const float* Ap0 = A + (size_t)ar0 * IN_DIM + lq * 8;
  const float* Ap1 = A + (size_t)ar1 * IN_DIM + lq * 8;

  auto stageB = [&](int buf, int k0) {
    #pragma unroll
    for (int j = 0; j < 4; ++j) {
      int i = j * 256 + tid;
      int r = i >> 3;
      int c = ((i & 7) ^ (r & 7)) * 8;
      __builtin_amdgcn_global_load_lds((const uint*)(WT + (size_t)r * IN_DIM + k0 + c),
                                       (uint*)&lB[buf][i * 8], 16, 0, 0);
    }
  };

  float4 fa0[4], fa1[4];
  auto loadA = [&](int k0) {
    const float* p0 = Ap0 + k0;
    fa0[0] = *(const float4*)p0;
    fa0[1] = *(const float4*)(p0 + 4);
    fa0[2] = *(const float4*)(p0 + 32);
    fa0[3] = *(const float4*)(p0 + 36);
    const float* p1 = Ap1 + k0;
    fa1[0] = *(const float4*)p1;
    fa1[1] = *(const float4*)(p1 + 4);
    fa1[2] = *(const float4*)(p1 + 32);
    fa1[3] = *(const float4*)(p1 + 36);
  };

  f32x4 acc0[8], acc1[8];
  #pragma unroll
  for (int n = 0; n < 8; ++n) {
    acc0[n] = (f32x4){0.f, 0.f, 0.f, 0.f};
    acc1[n] = (f32x4){0.f, 0.f, 0.f, 0.f};
  }

  loadA(0);
  stageB(0, 0);
  __syncthreads();

  constexpr int NT = IN_DIM / 64;
  for (int t = 0; t < NT; ++t) {
    const int cur = t & 1;
    bf16x8 av0[2], av1[2];
    {
      uint* u = (uint*)&av0[0];
      u[0] = cvtpk(fa0[0].x, fa0[0].y); u[1] = cvtpk(fa0[0].z, fa0[0].w);
      u[2] = cvtpk(fa0[1].x, fa0[1].y); u[3] = cvtpk(fa0[1].z, fa0[1].w);
      u[4] = cvtpk(fa0[2].x, fa0[2].y); u[5] = cvtpk(fa0[2].z, fa0[2].w);
      u[6] = cvtpk(fa0[3].x, fa0[3].y); u[7] = cvtpk(fa0[3].z, fa0[3].w);
      uint* v = (uint*)&av1[0];
      v[0] = cvtpk(fa1[0].x, fa1[0].y); v[1] = cvtpk(fa1[0].z, fa1[0].w);
      v[2] = cvtpk(fa1[1].x, fa1[1].y); v[3] = cvtpk(fa1[1].z, fa1[1].w);
      v[4] = cvtpk(fa1[2].x, fa1[2].y); v[5] = cvtpk(fa1[2].z, fa1[2].w);
      v[6] = cvtpk(fa1[3].x, fa1[3].y); v[7] = cvtpk(fa1[3].z, fa1[3].w);
    }
    if (t + 1 < NT) { loadA((t + 1) * 64); stageB(cur ^ 1, (t + 1) * 64); }
    #pragma unroll
    for (int kk = 0; kk < 2; ++kk) {
      #pragma unroll
      for (int n = 0; n < 8; ++n) {
        int C = n * 16 + lr;
        int slot = (kk * 4 + lq) ^ (C & 7);
        bf16x8 bv = *(const bf16x8*)&lB[cur][C * 64 + slot * 8];
        acc0[n] = __builtin_amdgcn_mfma_f32_16x16x32_bf16(av0[kk], bv, acc0[n], 0, 0, 0);
        acc1[n] = __builtin_amdgcn_mfma_f32_16x16x32_bf16(av1[kk], bv, acc1[n], 0, 0, 0);
      }
    }
    __syncthreads();
  }

  #pragma unroll
  for (int i = 0; i < 4; ++i) {
    int row0 = rb + lq * 4 + i;
    int row1 = rb + 64 + lq * 4 + i;
    float dv0 = (row0 < N) ? dinv[row0] : 0.f;
    float dv1 = (row1 < N) ? dinv[row1] : 0.f;
    #pragma unroll
    for (int n = 0; n < 8; ++n) {
      if (row0 < N) G[(size_t)row0 * HID + n * 16 + lr] = f2bf(dv0 * acc0[n][i]);
      if (row1 < N) G[(size_t)row1 * HID + n * 16 + lr] = f2bf(dv1 * acc1[n][i]);
    }
  }
}

// scatter into group-major CSR with packed local-node index
__device__ __forceinline__
void scatter2_body(const int* __restrict__ src, const int* __restrict__ dst,
                   const int* __restrict__ pos, const int* __restrict__ segstart,
                   uint* __restrict__ srcs2, int E, int N, int b) {
  int e0 = (b * 256 + threadIdx.x) * 8;
  if (e0 + 8 <= E) {
    int s[8], d[8], p[8];
    *(int4*)&s[0] = *(const int4*)&src[e0];
    *(int4*)&s[4] = *(const int4*)&src[e0 + 4];
    *(int4*)&d[0] = *(const int4*)&dst[e0];
    *(int4*)&d[4] = *(const int4*)&dst[e0 + 4];
    *(int4*)&p[0] = *(const int4*)&pos[e0];
    *(int4*)&p[4] = *(const int4*)&pos[e0 + 4];
    int st[8];
    #pragma unroll
    for (int j = 0; j < 8; ++j) st[j] = segstart[(s[j] >> GSH) * N + d[j]];
    #pragma unroll
    for (int j = 0; j < 8; ++j)
      srcs2[st[j] + p[j]] = (uint)s[j] | ((uint)(d[j] % MNODES) << 20);
  } else {
    for (int e = e0; e < E; ++e) {
      int ss = src[e], dd = dst[e];
      srcs2[segstart[(ss >> GSH) * N + dd] + pos[e]] =
          (uint)ss | ((uint)(dd % MNODES) << 20);
    }
  }
}

// mega: 3-slot pattern — 1x gemm1, 2x scatter
__global__ __launch_bounds__(256)
void k_mega(const float* __restrict__ A, const ushort* __restrict__ WT,
            const float* __restrict__ dinv, ushort* __restrict__ G, int N,
            const int* __restrict__ src, const int* __restrict__ dst,
            const int* __restrict__ pos, const int* __restrict__ segstart,
            uint* __restrict__ srcs2, int E, int Gg1, int Gsc) {
  __shared__ ushort lB[2][128 * 64];
  int grp = blockIdx.x / 3, slot = blockIdx.x % 3;
  if (slot == 0) {
    if (grp < Gg1) gemm1_body(lB, A, WT, dinv, G, N, grp);
  } else {
    int b = grp * 2 + (slot - 1);
    if (b < Gsc) scatter2_body(src, dst, pos, segstart, srcs2, E, N, b);
  }
}

// ---------------- persistent-block phased aggregation ----------------
// G rows pre-scaled by dinv[src]; G[N] = 0 (sentinel). Block owns MNODES
// contiguous nodes; acc f32 in LDS over 64 dims per sweep; all blocks
// co-resident and sweep src-groups in the same order (natural convoying).
__global__ __launch_bounds__(256)
void k_pagg(const uint* __restrict__ Gp, const uint* __restrict__ srcs2,
            const int* __restrict__ segstart, const float* __restrict__ dinv,
            const float* __restrict__ bias, uint* __restrict__ Ou,
            int N, int NG) {
  __shared__ float acc[MNODES * 64];
  const int tid = threadIdx.x;
  const int lane = tid & 63;
  const int wid = tid >> 6;
  const int l32 = lane & 31, half = lane >> 5;
  const int nfirst = blockIdx.x * MNODES;
  const int nendb = min(N, nfirst + MNODES);
  const int w0 = min(nendb, nfirst + wid * 49);
  const int w1 = min(nendb, w0 + 49);

  for (int sweep = 0; sweep < 2; ++sweep) {
    // init acc = self term (G row, pre-scaled by dinv[n])
    for (int n = w0 + half; n < w1; n += 2) {
      uint v = Gp[(size_t)n * 64 + sweep * 32 + l32];
      int local = n - nfirst;
      acc[local * 64 + 2 * l32]     = lof(v);
      acc[local * 64 + 2 * l32 + 1] = hif(v);
    }
    // phases over src-groups (no sync: locality via convoying only)
    for (int g = 0; g < NG; ++g) {
      if (w0 >= w1) continue;
      int A = segstart[(size_t)g * N + w0];
      int B = segstart[(size_t)g * N + w1];
      for (int i = A; i < B; i += 16) {
        uint e[8];
        #pragma unroll
        for (int j = 0; j < 8; ++j) {
          int idx = i + half * 8 + j;
          e[j] = (idx < B) ? srcs2[idx] : (uint)N;   // sentinel: G[N]=0, local 0
        }
        uint v[8];
        #pragma unroll
        for (int j = 0; j < 8; ++j)
          v[j] = Gp[(size_t)(e[j] & 0xFFFFFu) * 64 + sweep * 32 + l32];
        __builtin_amdgcn_sched_barrier(0);
        #pragma unroll
        for (int j = 0; j < 8; ++j) {
          int local = e[j] >> 20;
          atomicAdd(&acc[local * 64 + 2 * l32],     lof(v[j]));
          atomicAdd(&acc[local * 64 + 2 * l32 + 1], hif(v[j]));
        }
      }
    }
    __syncthreads();   // acc stable before read-back (halves share rows)
    // writeback: h = relu(dinv*acc + bias) -> bf16
    for (int n = w0 + half; n < w1; n += 2) {
      int local = n - nfirst;
      float a0 = acc[local * 64 + 2 * l32];
      float a1 = acc[local * 64 + 2 * l32 + 1];
      float di = dinv[n];
      float2 bb = ((const float2*)bias)[sweep * 32 + l32];
      a0 = fmaxf(fmaf(di, a0, bb.x), 0.f);
      a1 = fmaxf(fmaf(di, a1, bb.y), 0.f);
      Ou[(size_t)n * 64 + sweep * 32 + l32] = (uint)f2bf(a0) | ((uint)f2bf(a1) << 16);
    }
    __syncthreads();   // before acc reuse in next sweep
  }
}

// ---------------- GEMM2 (r10-proven verbatim) ----------------
__global__ __launch_bounds__(256)
void k_gemm2(const ushort* __restrict__ A, const ushort* __restrict__ WT,
             const float* __restrict__ dinv, ushort* __restrict__ G, const int N) {
  __shared__ ushort lA[2][128 * 64];
  __shared__ ushort lB[2][128 * 64];
  const int tid = threadIdx.x;
  const int lane = tid & 63;
  const int wid = tid >> 6;
  const int wm = wid >> 1, wn = wid & 1;
  const int row0 = blockIdx.x * 128;
  const int lr = lane & 15;
  const int lk8 = lane >> 4;
  constexpr int K = HID;

  auto stage = [&](int buf, int k0) {
    #pragma unroll
    for (int j = 0; j < 4; ++j) {
      int i = j * 256 + tid;
      int r = i >> 3;
      int c = ((i & 7) ^ (r & 7)) * 8;
      int ga = row0 + r; ga = ga < N ? ga : N - 1;
      __builtin_amdgcn_global_load_lds((const uint*)(A + (size_t)ga * K + k0 + c),
                                       (uint*)&lA[buf][i * 8], 16, 0, 0);
      __builtin_amdgcn_global_load_lds((const uint*)(WT + (size_t)r * K + k0 + c),
                                       (uint*)&lB[buf][i * 8], 16, 0, 0);
    }
  };

  f32x4 acc[4][4];
  #pragma unroll
  for (int m = 0; m < 4; ++m)
    #pragma unroll
    for (int n = 0; n < 4; ++n)
      acc[m][n] = (f32x4){0.f, 0.f, 0.f, 0.f};

  constexpr int NT = K / 64;
  stage(0, 0);
  __syncthreads();

  for (int t = 0; t < NT; ++t) {
    const int cur = t & 1;
    if (t + 1 < NT) stage(cur ^ 1, (t + 1) * 64);
    #pragma unroll
    for (int kk = 0; kk < 2; ++kk) {
      bf16x8 av[4], bv[4];
      #pragma unroll
      for (int m = 0; m < 4; ++m) {
        int R = wm * 64 + m * 16 + lr;
        int slot = (kk * 4 + lk8) ^ (R & 7);
        av[m] = *(const bf16x8*)&lA[cur][R * 64 + slot * 8];
      }
      #pragma unroll
      for (int n = 0; n < 4; ++n) {
        int C = wn * 64 + n * 16 + lr;
        int slot = (kk * 4 + lk8) ^ (C & 7);
        bv[n] = *(const bf16x8*)&lB[cur][C * 64 + slot * 8];
      }
      #pragma unroll
      for (int m = 0; m < 4; ++m)
        #pragma unroll
        for (int n = 0; n < 4; ++n)
          acc[m][n] = __builtin_amdgcn_mfma_f32_16x16x32_bf16(av[m], bv[n], acc[m][n], 0, 0, 0);
    }
    __syncthreads();
  }

  #pragma unroll
  for (int m = 0; m < 4; ++m) {
    #pragma unroll
    for (int i = 0; i < 4; ++i) {
      int row = row0 + wm * 64 + m * 16 + (lane >> 4) * 4 + i;
      if (row < N) {
        float dv = dinv[row];
        #pragma unroll
        for (int n = 0; n < 4; ++n) {
          int col = wn * 64 + n * 16 + lr;
          G[(size_t)row * HID + col] = f2bf(dv * acc[m][n][i]);
        }
      }
    }
  }
}

// ---------------- classifier (r2-proven): [N,128] bf16 @ [128,7] + bc -> f32 ----------------
__global__ void k_gemm3(const ushort* __restrict__ A, const float* __restrict__ Wc,
                        const float* __restrict__ bc, float* __restrict__ out, int N) {
  __shared__ float w[HID * NC];
  __shared__ float bb[NC];
  for (int i = threadIdx.x; i < HID * NC; i += 256) w[i] = Wc[i];
  if (threadIdx.x < NC) bb[threadIdx.x] = bc[threadIdx.x];
  __syncthreads();
  int r = blockIdx.x * 256 + threadIdx.x;
  if (r >= N) return;
  float acc[NC];
  #pragma unroll
  for (int c = 0; c < NC; ++c) acc[c] = bb[c];
  const uint* Au = (const uint*)(A + (size_t)r * HID);
  #pragma unroll 4
  for (int kw = 0; kw < HID / 2; ++kw) {
    uint v = Au[kw];
    float v0 = lof(v);
    float v1 = hif(v);
    const float* w0 = &w[(kw * 2) * NC];
    #pragma unroll
    for (int c = 0; c < NC; ++c) acc[c] += v0 * w0[c] + v1 * w0[NC + c];
  }
  #pragma unroll
  for (int c = 0; c < NC; ++c) out[(size_t)r * NC + c] = acc[c];
}

extern "C" void kernel_launch(void* const* d_in, const int* in_sizes, int n_in,
                              void* d_out, int out_size, void* d_ws, size_t ws_size,
                              hipStream_t stream) {
  const float* x  = (const float*)d_in[0];
  const int*   ei = (const int*)d_in[1];
  const float* W1 = (const float*)d_in[2];
  const float* b1 = (const float*)d_in[3];
  const float* W2 = (const float*)d_in[4];
  const float* b2 = (const float*)d_in[5];
  const float* Wc = (const float*)d_in[6];
  const float* bc = (const float*)d_in[7];
  float* out = (float*)d_out;

  const int N = in_sizes[0] / IN_DIM;
  const int E = in_sizes[1] / 2;
  const int* src = ei;
  const int* dst = ei + E;
  const int NG = ((N - 1) >> GSH) + 1;           // 13 src-groups
  const long L = (long)NG * N;                   // 1.3M (g,dst) cells
  const int NCH = (int)((L + 16383) / 16384);    // 80 scan chunks (<=128)
  const long NPAD = (long)NCH * 16384;

  char* ws = (char*)d_ws;
  size_t off = 0;
  auto alloc = [&](size_t bytes) -> void* {
    off = (off + 255) & ~(size_t)255;
    void* p = ws + off;
    off += bytes;
    return p;
  };
  ushort* H0     = (ushort*)alloc((size_t)(N + 1) * HID * 2);  // G; row N = 0
  ushort* H1     = (ushort*)alloc((size_t)(N + 1) * HID * 2);
  uint*   srcs2  = (uint*)alloc((size_t)E * 4);
  int*    cnt2   = (int*)alloc((size_t)NPAD * 4);
  int*    segst  = (int*)alloc((size_t)(NPAD + 64) * 4);
  int*    pos    = (int*)alloc((size_t)E * 4);
  float*  dinv   = (float*)alloc((size_t)N * 4);
  int*    partials = (int*)alloc(512);
  ushort* W1T    = (ushort*)alloc((size_t)IN_DIM * HID * 2);
  ushort* W2T    = (ushort*)alloc((size_t)HID * HID * 2);

  hipMemsetAsync(cnt2, 0, (size_t)NPAD * 4, stream);
  hipMemsetAsync(H0 + (size_t)N * HID, 0, HID * 2, stream);   // G[N] = 0

  k_convW<<<(IN_DIM * HID + 255) / 256, 256, 0, stream>>>(W1, W1T, IN_DIM);
  k_convW<<<(HID * HID + 255) / 256, 256, 0, stream>>>(W2, W2T, HID);

  k_count2<<<(E + 1023) / 1024, 256, 0, stream>>>(src, dst, cnt2, pos, E, N);
  k_deg<<<(N + 255) / 256, 256, 0, stream>>>(cnt2, dinv, N, NG);
  k_scanP2<<<NCH, 256, 0, stream>>>(cnt2, partials);
  k_scanC2<<<1, 128, 0, stream>>>(partials, NCH);
  k_scanF2<<<NCH, 256, 0, stream>>>(cnt2, partials, segst);

  // mega: gemm1 || scatter (3-slot pattern 1:2)
  const int Gg1 = (N + 127) / 128;
  const int Gsc = (E + 2047) / 2048;
  int ngroups = Gg1;
  if ((Gsc + 1) / 2 > ngroups) ngroups = (Gsc + 1) / 2;
  k_mega<<<ngroups * 3, 256, 0, stream>>>(x, W1T, dinv, H0, N,
                                          src, dst, pos, segst, srcs2, E, Gg1, Gsc);

  const int NBLK = (N + MNODES - 1) / MNODES;    // 511 persistent blocks
  k_pagg<<<NBLK, 256, 0, stream>>>((const uint*)H0, srcs2, segst, dinv, b1,
                                   (uint*)H1, N, NG);
  k_gemm2<<<(N + 127) / 128, 256, 0, stream>>>(H1, W2T, dinv, H0, N);
  k_pagg<<<NBLK, 256, 0, stream>>>((const uint*)H0, srcs2, segst, dinv, b2,
                                   (uint*)H1, N, NG);
  k_gemm3<<<(N + 255) / 256, 256, 0, stream>>>(H1, Wc, bc, out, N);
}

// Round 12
// 565.014 us; speedup vs baseline: 8.5204x; 8.5204x over previous
//
#include <hip/hip_runtime.h>
#include <hip/hip_bf16.h>

#define IN_DIM 768
#define HID 128
#define NC 7

typedef __attribute__((ext_vector_type(8))) short bf16x8;
typedef __attribute__((ext_vector_type(4))) float f32x4;

__device__ __forceinline__ ushort f2bf(float f) {
  uint u = __float_as_uint(f);
  u += 0x7fffu + ((u >> 16) & 1u);   // round-to-nearest-even
  return (ushort)(u >> 16);
}
__device__ __forceinline__ float lof(uint v) { return __uint_as_float(v << 16); }
__device__ __forceinline__ float hif(uint v) { return __uint_as_float(v & 0xffff0000u); }
__device__ __forceinline__ uint cvtpk(float lo, float hi) {
  uint r;
  asm("v_cvt_pk_bf16_f32 %0, %1, %2" : "=v"(r) : "v"(lo), "v"(hi));
  return r;
}

// ---------------- CSR build (r6/r9-proven) ----------------

__global__ __launch_bounds__(256) void k_count(const int* __restrict__ dst,
                                               int* __restrict__ cnt,
                                               int* __restrict__ pos, int E) {
  int e0 = (blockIdx.x * 256 + threadIdx.x) * 4;
  if (e0 + 4 <= E) {
    int4 d = *(const int4*)&dst[e0];
    int4 p;
    p.x = atomicAdd(&cnt[d.x], 1);
    p.y = atomicAdd(&cnt[d.y], 1);
    p.z = atomicAdd(&cnt[d.z], 1);
    p.w = atomicAdd(&cnt[d.w], 1);
    *(int4*)&pos[e0] = p;
  } else {
    for (int e = e0; e < E; ++e) pos[e] = atomicAdd(&cnt[dst[e]], 1);
  }
}

__device__ __forceinline__ int pad4(int c) { return (c + 3) & ~3; }

__global__ void k_scan_partial(const int* __restrict__ cnt, int* __restrict__ partials, int N) {
  __shared__ int sm[256];
  int b = blockIdx.x, t = threadIdx.x;
  int base = b * 1024 + t * 4;
  int s = 0;
  #pragma unroll
  for (int j = 0; j < 4; ++j) if (base + j < N) s += pad4(cnt[base + j]);
  sm[t] = s;
  __syncthreads();
  for (int off = 128; off > 0; off >>= 1) {
    if (t < off) sm[t] += sm[t + off];
    __syncthreads();
  }
  if (t == 0) partials[b] = sm[0];
}

__global__ void k_scan_combine(int* __restrict__ partials, int* __restrict__ rowptr,
                               int nch, int N) {
  __shared__ int sm[128];
  int t = threadIdx.x;
  int v0 = (t < nch) ? partials[t] : 0;
  sm[t] = v0;
  __syncthreads();
  for (int off = 1; off < 128; off <<= 1) {
    int add = (t >= off) ? sm[t - off] : 0;
    __syncthreads();
    sm[t] += add;
    __syncthreads();
  }
  if (t < nch) partials[t] = sm[t] - v0;
  if (t == 0) rowptr[N] = sm[127];
}

__global__ void k_scan_final(const int* __restrict__ cnt, const int* __restrict__ chunkoff,
                             int* __restrict__ rowptr, int N) {
  __shared__ int sm[256];
  int b = blockIdx.x, t = threadIdx.x;
  int base = b * 1024 + t * 4;
  int v[4]; int s = 0;
  #pragma unroll
  for (int j = 0; j < 4; ++j) { v[j] = (base + j < N) ? pad4(cnt[base + j]) : 0; s += v[j]; }
  sm[t] = s;
  __syncthreads();
  for (int off = 1; off < 256; off <<= 1) {
    int add = (t >= off) ? sm[t - off] : 0;
    __syncthreads();
    sm[t] += add;
    __syncthreads();
  }
  int excl = sm[t] - s;
  int run = chunkoff[b] + excl;
  #pragma unroll
  for (int j = 0; j < 4; ++j) {
    if (base + j < N) rowptr[base + j] = run;
    run += v[j];
  }
}

__global__ void k_dinv(const int* __restrict__ cnt, float* __restrict__ dinv, int N) {
  int n = blockIdx.x * 256 + threadIdx.x;
  if (n < N) dinv[n] = rsqrtf((float)(cnt[n] + 1));
}

// ---------------- weight convert/transpose (r6-proven) ----------------
__global__ void k_convW(const float* __restrict__ W, ushort* __restrict__ WT, int K) {
  int i = blockIdx.x * 256 + threadIdx.x;
  if (i >= K * HID) return;
  int k = i >> 7, c = i & 127;
  WT[c * K + k] = f2bf(W[i]);
}

// ---------------- device bodies for the mega kernel ----------------

// gemm1 body: x[N,768] f32 @ WT[128,768] -> G = dinv*(x@W1) bf16.
__device__ __forceinline__
void gemm1_body(ushort (*lB)[128 * 64],
                const float* __restrict__ A, const ushort* __restrict__ WT,
                const float* __restrict__ dinv, ushort* __restrict__ G,
                const int N, int b) {
  const int tid = threadIdx.x;
  const int lane = tid & 63;
  const int wid = tid >> 6;                    // 0..3
  const int lr = lane & 15, lq = lane >> 4;    // lq 0..3
  const int rb = b * 128 + wid * 16;           // half-0 row base for this wave
  int ar0 = rb + lr;      if (ar0 > N - 1) ar0 = N - 1;
  int ar1 = rb + 64 + lr; if (ar1 > N - 1) ar1 = N - 1;
  const float* Ap0 = A + (size_t)ar0 * IN_DIM + lq * 8;
  const float* Ap1 = A + (size_t)ar1 * IN_DIM + lq * 8;

  auto stageB = [&](int buf, int k0) {
    #pragma unroll
    for (int j = 0; j < 4; ++j) {
      int i = j * 256 + tid;
      int r = i >> 3;
      int c = ((i & 7) ^ (r & 7)) * 8;
      __builtin_amdgcn_global_load_lds((const uint*)(WT + (size_t)r * IN_DIM + k0 + c),
                                       (uint*)&lB[buf][i * 8], 16, 0, 0);
    }
  };

  float4 fa0[4], fa1[4];
  auto loadA = [&](int k0) {
    const float* p0 = Ap0 + k0;
    fa0[0] = *(const float4*)p0;
    fa0[1] = *(const float4*)(p0 + 4);
    fa0[2] = *(const float4*)(p0 + 32);
    fa0[3] = *(const float4*)(p0 + 36);
    const float* p1 = Ap1 + k0;
    fa1[0] = *(const float4*)p1;
    fa1[1] = *(const float4*)(p1 + 4);
    fa1[2] = *(const float4*)(p1 + 32);
    fa1[3] = *(const float4*)(p1 + 36);
  };

  f32x4 acc0[8], acc1[8];
  #pragma unroll
  for (int n = 0; n < 8; ++n) {
    acc0[n] = (f32x4){0.f, 0.f, 0.f, 0.f};
    acc1[n] = (f32x4){0.f, 0.f, 0.f, 0.f};
  }

  loadA(0);
  stageB(0, 0);
  __syncthreads();

  constexpr int NT = IN_DIM / 64;
  for (int t = 0; t < NT; ++t) {
    const int cur = t & 1;
    bf16x8 av0[2], av1[2];
    {
      uint* u = (uint*)&av0[0];
      u[0] = cvtpk(fa0[0].x, fa0[0].y); u[1] = cvtpk(fa0[0].z, fa0[0].w);
      u[2] = cvtpk(fa0[1].x, fa0[1].y); u[3] = cvtpk(fa0[1].z, fa0[1].w);
      u[4] = cvtpk(fa0[2].x, fa0[2].y); u[5] = cvtpk(fa0[2].z, fa0[2].w);
      u[6] = cvtpk(fa0[3].x, fa0[3].y); u[7] = cvtpk(fa0[3].z, fa0[3].w);
      uint* v = (uint*)&av1[0];
      v[0] = cvtpk(fa1[0].x, fa1[0].y); v[1] = cvtpk(fa1[0].z, fa1[0].w);
      v[2] = cvtpk(fa1[1].x, fa1[1].y); v[3] = cvtpk(fa1[1].z, fa1[1].w);
      v[4] = cvtpk(fa1[2].x, fa1[2].y); v[5] = cvtpk(fa1[2].z, fa1[2].w);
      v[6] = cvtpk(fa1[3].x, fa1[3].y); v[7] = cvtpk(fa1[3].z, fa1[3].w);
    }
    if (t + 1 < NT) { loadA((t + 1) * 64); stageB(cur ^ 1, (t + 1) * 64); }
    #pragma unroll
    for (int kk = 0; kk < 2; ++kk) {
      #pragma unroll
      for (int n = 0; n < 8; ++n) {
        int C = n * 16 + lr;
        int slot = (kk * 4 + lq) ^ (C & 7);
        bf16x8 bv = *(const bf16x8*)&lB[cur][C * 64 + slot * 8];
        acc0[n] = __builtin_amdgcn_mfma_f32_16x16x32_bf16(av0[kk], bv, acc0[n], 0, 0, 0);
        acc1[n] = __builtin_amdgcn_mfma_f32_16x16x32_bf16(av1[kk], bv, acc1[n], 0, 0, 0);
      }
    }
    __syncthreads();
  }

  #pragma unroll
  for (int i = 0; i < 4; ++i) {
    int row0 = rb + lq * 4 + i;
    int row1 = rb + 64 + lq * 4 + i;
    float dv0 = (row0 < N) ? dinv[row0] : 0.f;
    float dv1 = (row1 < N) ? dinv[row1] : 0.f;
    #pragma unroll
    for (int n = 0; n < 8; ++n) {
      if (row0 < N) G[(size_t)row0 * HID + n * 16 + lr] = f2bf(dv0 * acc0[n][i]);
      if (row1 < N) G[(size_t)row1 * HID + n * 16 + lr] = f2bf(dv1 * acc1[n][i]);
    }
  }
}

// scatter body
__device__ __forceinline__
void scatter_body(const int* __restrict__ src, const int* __restrict__ dst,
                  const int* __restrict__ pos, const int* __restrict__ rowptr,
                  int* __restrict__ srcs, int E, int b) {
  int e0 = (b * 256 + threadIdx.x) * 8;
  if (e0 + 8 <= E) {
    int s[8], d[8], p[8];
    *(int4*)&s[0] = *(const int4*)&src[e0];
    *(int4*)&s[4] = *(const int4*)&src[e0 + 4];
    *(int4*)&d[0] = *(const int4*)&dst[e0];
    *(int4*)&d[4] = *(const int4*)&dst[e0 + 4];
    *(int4*)&p[0] = *(const int4*)&pos[e0];
    *(int4*)&p[4] = *(const int4*)&pos[e0 + 4];
    int rp[8];
    #pragma unroll
    for (int j = 0; j < 8; ++j) rp[j] = rowptr[d[j]];
    #pragma unroll
    for (int j = 0; j < 8; ++j) srcs[rp[j] + p[j]] = s[j];
  } else {
    for (int e = e0; e < E; ++e) srcs[rowptr[dst[e]] + pos[e]] = src[e];
  }
}

// pad-fill body: write only the <=3 pad slots per row (src = N, G[N] = 0)
__device__ __forceinline__
void fillpad_body(const int* __restrict__ cnt, const int* __restrict__ rowptr,
                  int* __restrict__ srcs, int N, int b) {
  int n = b * 256 + threadIdx.x;
  if (n < N) {
    int c = cnt[n];
    int e0 = rowptr[n] + c;
    int e1 = rowptr[n] + pad4(c);
    for (int i = e0; i < e1; ++i) srcs[i] = N;
  }
}

// mega kernel: 7-slot role pattern per group — 2x gemm1, 4x scatter, 1x fillpad
__global__ __launch_bounds__(256)
void k_mega(const float* __restrict__ A, const ushort* __restrict__ WT,
            const float* __restrict__ dinv, ushort* __restrict__ G, int N,
            const int* __restrict__ src, const int* __restrict__ dst,
            const int* __restrict__ pos, const int* __restrict__ rowptr,
            int* __restrict__ srcs, int E, const int* __restrict__ cnt,
            int Gg1, int Gsc, int Gfp) {
  __shared__ ushort lB[2][128 * 64];
  int grp = blockIdx.x / 7, slot = blockIdx.x % 7;
  if (slot < 2) {
    int b = grp * 2 + slot;
    if (b < Gg1) gemm1_body(lB, A, WT, dinv, G, N, b);
  } else if (slot < 6) {
    int b = grp * 4 + (slot - 2);
    if (b < Gsc) scatter_body(src, dst, pos, rowptr, srcs, E, b);
  } else {
    if (grp < Gfp) fillpad_body(cnt, rowptr, srcs, N, grp);
  }
}

// ---------------- GEMM2: H1[N,128] bf16 @ WT[128,128] -> G = dinv*(H1@W2), bf16 ----------------
__global__ __launch_bounds__(256)
void k_gemm2(const ushort* __restrict__ A, const ushort* __restrict__ WT,
             const float* __restrict__ dinv, ushort* __restrict__ G, const int N) {
  __shared__ ushort lA[2][128 * 64];
  __shared__ ushort lB[2][128 * 64];
  const int tid = threadIdx.x;
  const int lane = tid & 63;
  const int wid = tid >> 6;
  const int wm = wid >> 1, wn = wid & 1;
  const int row0 = blockIdx.x * 128;
  const int lr = lane & 15;
  const int lk8 = lane >> 4;
  constexpr int K = HID;

  auto stage = [&](int buf, int k0) {
    #pragma unroll
    for (int j = 0; j < 4; ++j) {
      int i = j * 256 + tid;
      int r = i >> 3;
      int c = ((i & 7) ^ (r & 7)) * 8;
      int ga = row0 + r; ga = ga < N ? ga : N - 1;
      __builtin_amdgcn_global_load_lds((const uint*)(A + (size_t)ga * K + k0 + c),
                                       (uint*)&lA[buf][i * 8], 16, 0, 0);
      __builtin_amdgcn_global_load_lds((const uint*)(WT + (size_t)r * K + k0 + c),
                                       (uint*)&lB[buf][i * 8], 16, 0, 0);
    }
  };

  f32x4 acc[4][4];
  #pragma unroll
  for (int m = 0; m < 4; ++m)
    #pragma unroll
    for (int n = 0; n < 4; ++n)
      acc[m][n] = (f32x4){0.f, 0.f, 0.f, 0.f};

  constexpr int NT = K / 64;
  stage(0, 0);
  __syncthreads();

  for (int t = 0; t < NT; ++t) {
    const int cur = t & 1;
    if (t + 1 < NT) stage(cur ^ 1, (t + 1) * 64);
    #pragma unroll
    for (int kk = 0; kk < 2; ++kk) {
      bf16x8 av[4], bv[4];
      #pragma unroll
      for (int m = 0; m < 4; ++m) {
        int R = wm * 64 + m * 16 + lr;
        int slot = (kk * 4 + lk8) ^ (R & 7);
        av[m] = *(const bf16x8*)&lA[cur][R * 64 + slot * 8];
      }
      #pragma unroll
      for (int n = 0; n < 4; ++n) {
        int C = wn * 64 + n * 16 + lr;
        int slot = (kk * 4 + lk8) ^ (C & 7);
        bv[n] = *(const bf16x8*)&lB[cur][C * 64 + slot * 8];
      }
      #pragma unroll
      for (int m = 0; m < 4; ++m)
        #pragma unroll
        for (int n = 0; n < 4; ++n)
          acc[m][n] = __builtin_amdgcn_mfma_f32_16x16x32_bf16(av[m], bv[n], acc[m][n], 0, 0, 0);
    }
    __syncthreads();
  }

  #pragma unroll
  for (int m = 0; m < 4; ++m) {
    #pragma unroll
    for (int i = 0; i < 4; ++i) {
      int row = row0 + wm * 64 + m * 16 + (lane >> 4) * 4 + i;
      if (row < N) {
        float dv = dinv[row];
        #pragma unroll
        for (int n = 0; n < 4; ++n) {
          int col = wn * 64 + n * 16 + lr;
          G[(size_t)row * HID + col] = f2bf(dv * acc[m][n][i]);
        }
      }
    }
  }
}

// ---------------- aggregation: full-row gathers, 32-deep pipeline (r6-proven) ----------------
// G rows pre-scaled by dinv[src]; pad src = N with G[N] = 0.

#define GL(v, s) uint v = Gp[(size_t)(s) * 64 + lane];
#define AC(v) { a0 += lof(v); a1 += hif(v); }

__device__ __forceinline__ void agg32(const uint* __restrict__ Gp,
                                      const int* __restrict__ srcs,
                                      int i, int lane, float& a0, float& a1) {
  int4 sa = *(const int4*)&srcs[i];
  int4 sb = *(const int4*)&srcs[i + 4];
  int4 sc = *(const int4*)&srcs[i + 8];
  int4 sd = *(const int4*)&srcs[i + 12];
  int4 se = *(const int4*)&srcs[i + 16];
  int4 sf = *(const int4*)&srcs[i + 20];
  int4 sg = *(const int4*)&srcs[i + 24];
  int4 sh = *(const int4*)&srcs[i + 28];
  GL(h00, sa.x) GL(h01, sa.y) GL(h02, sa.z) GL(h03, sa.w)
  GL(h04, sb.x) GL(h05, sb.y) GL(h06, sb.z) GL(h07, sb.w)
  GL(h08, sc.x) GL(h09, sc.y) GL(h10, sc.z) GL(h11, sc.w)
  GL(h12, sd.x) GL(h13, sd.y) GL(h14, sd.z) GL(h15, sd.w)
  GL(h16, se.x) GL(h17, se.y) GL(h18, se.z) GL(h19, se.w)
  GL(h20, sf.x) GL(h21, sf.y) GL(h22, sf.z) GL(h23, sf.w)
  GL(h24, sg.x) GL(h25, sg.y) GL(h26, sg.z) GL(h27, sg.w)
  GL(h28, sh.x) GL(h29, sh.y) GL(h30, sh.z) GL(h31, sh.w)
  __builtin_amdgcn_sched_barrier(0);
  AC(h00) AC(h01) AC(h02) AC(h03) AC(h04) AC(h05) AC(h06) AC(h07)
  AC(h08) AC(h09) AC(h10) AC(h11) AC(h12) AC(h13) AC(h14) AC(h15)
  AC(h16) AC(h17) AC(h18) AC(h19) AC(h20) AC(h21) AC(h22) AC(h23)
  AC(h24) AC(h25) AC(h26) AC(h27) AC(h28) AC(h29) AC(h30) AC(h31)
}

__device__ __forceinline__ void agg16(const uint* __restrict__ Gp,
                                      const int* __restrict__ srcs,
                                      int i, int lane, float& a0, float& a1) {
  int4 sa = *(const int4*)&srcs[i];
  int4 sb = *(const int4*)&srcs[i + 4];
  int4 sc = *(const int4*)&srcs[i + 8];
  int4 sd = *(const int4*)&srcs[i + 12];
  GL(h00, sa.x) GL(h01, sa.y) GL(h02, sa.z) GL(h03, sa.w)
  GL(h04, sb.x) GL(h05, sb.y) GL(h06, sb.z) GL(h07, sb.w)
  GL(h08, sc.x) GL(h09, sc.y) GL(h10, sc.z) GL(h11, sc.w)
  GL(h12, sd.x) GL(h13, sd.y) GL(h14, sd.z) GL(h15, sd.w)
  __builtin_amdgcn_sched_barrier(0);
  AC(h00) AC(h01) AC(h02) AC(h03) AC(h04) AC(h05) AC(h06) AC(h07)
  AC(h08) AC(h09) AC(h10) AC(h11) AC(h12) AC(h13) AC(h14) AC(h15)
}

__device__ __forceinline__ void agg4(const uint* __restrict__ Gp,
                                     const int* __restrict__ srcs,
                                     int i, int lane, float& a0, float& a1) {
  int4 sa = *(const int4*)&srcs[i];
  GL(h00, sa.x) GL(h01, sa.y) GL(h02, sa.z) GL(h03, sa.w)
  __builtin_amdgcn_sched_barrier(0);
  AC(h00) AC(h01) AC(h02) AC(h03)
}

__global__ __launch_bounds__(256)
void k_agg(const uint* __restrict__ Gp, const int* __restrict__ srcs,
           const int* __restrict__ rowptr, const float* __restrict__ dinv,
           const float* __restrict__ bias, uint* __restrict__ Ou, int N) {
  int w = (blockIdx.x * 256 + threadIdx.x) >> 6;
  if (w >= N) return;
  int lane = threadIdx.x & 63;
  int start = rowptr[w], end = rowptr[w + 1];
  float di = dinv[w];
  uint hv = Gp[(size_t)w * 64 + lane];
  float a0 = lof(hv), a1 = hif(hv);
  int i = start;
  for (; i + 32 <= end; i += 32) agg32(Gp, srcs, i, lane, a0, a1);
  for (; i + 16 <= end; i += 16) agg16(Gp, srcs, i, lane, a0, a1);
  for (; i < end; i += 4)        agg4(Gp, srcs, i, lane, a0, a1);
  float2 bb = ((const float2*)bias)[lane];
  a0 = fmaxf(fmaf(di, a0, bb.x), 0.f);
  a1 = fmaxf(fmaf(di, a1, bb.y), 0.f);
  Ou[(size_t)w * 64 + lane] = (uint)f2bf(a0) | ((uint)f2bf(a1) << 16);
}

__global__ __launch_bounds__(256)
void k_agg_final(const uint* __restrict__ Gp, const int* __restrict__ srcs,
                 const int* __restrict__ rowptr, const float* __restrict__ dinv,
                 const float* __restrict__ bias, const float* __restrict__ Wc,
                 const float* __restrict__ bc, float* __restrict__ out, int N) {
  int w = (blockIdx.x * 256 + threadIdx.x) >> 6;
  if (w >= N) return;
  int lane = threadIdx.x & 63;
  int start = rowptr[w], end = rowptr[w + 1];
  float di = dinv[w];
  uint hv = Gp[(size_t)w * 64 + lane];
  float a0 = lof(hv), a1 = hif(hv);
  int i = start;
  for (; i + 32 <= end; i += 32) agg32(Gp, srcs, i, lane, a0, a1);
  for (; i + 16 <= end; i += 16) agg16(Gp, srcs, i, lane, a0, a1);
  for (; i < end; i += 4)        agg4(Gp, srcs, i, lane, a0, a1);
  float2 bb = ((const float2*)bias)[lane];
  a0 = fmaxf(fmaf(di, a0, bb.x), 0.f);
  a1 = fmaxf(fmaf(di, a1, bb.y), 0.f);
  const float* w0 = &Wc[(2 * lane) * NC];
  #pragma unroll
  for (int c = 0; c < NC; ++c) {
    float s = a0 * w0[c] + a1 * w0[NC + c];
    #pragma unroll
    for (int off = 32; off > 0; off >>= 1) s += __shfl_xor(s, off, 64);
    if (lane == 0) out[(size_t)w * NC + c] = s + bc[c];
  }
}

extern "C" void kernel_launch(void* const* d_in, const int* in_sizes, int n_in,
                              void* d_out, int out_size, void* d_ws, size_t ws_size,
                              hipStream_t stream) {
  const float* x  = (const float*)d_in[0];
  const int*   ei = (const int*)d_in[1];
  const float* W1 = (const float*)d_in[2];
  const float* b1 = (const float*)d_in[3];
  const float* W2 = (const float*)d_in[4];
  const float* b2 = (const float*)d_in[5];
  const float* Wc = (const float*)d_in[6];
  const float* bc = (const float*)d_in[7];
  float* out = (float*)d_out;

  const int N = in_sizes[0] / IN_DIM;
  const int E = in_sizes[1] / 2;
  const int* src = ei;
  const int* dst = ei + E;
  const int CSRCAP = E + 3 * N + 64;

  char* ws = (char*)d_ws;
  size_t off = 0;
  auto alloc = [&](size_t bytes) -> void* {
    off = (off + 255) & ~(size_t)255;
    void* p = ws + off;
    off += bytes;
    return p;
  };
  ushort* H0     = (ushort*)alloc((size_t)(N + 1) * HID * 2);  // G buffers (row N = pad = 0)
  ushort* H1     = (ushort*)alloc((size_t)(N + 1) * HID * 2);
  int*    srcs   = (int*)alloc((size_t)CSRCAP * 4);
  int*    cnt    = (int*)alloc((size_t)N * 4);
  int*    pos    = (int*)alloc((size_t)E * 4);
  int*    rowptr = (int*)alloc((size_t)(N + 1) * 4);
  float*  dinv   = (float*)alloc((size_t)N * 4);
  int*    partials = (int*)alloc(512);
  ushort* W1T    = (ushort*)alloc((size_t)IN_DIM * HID * 2);
  ushort* W2T    = (ushort*)alloc((size_t)HID * HID * 2);

  hipMemsetAsync(cnt, 0, (size_t)N * 4, stream);
  hipMemsetAsync(H0 + (size_t)N * HID, 0, HID * 2, stream);   // pad row G[N] = 0

  k_convW<<<(IN_DIM * HID + 255) / 256, 256, 0, stream>>>(W1, W1T, IN_DIM);
  k_convW<<<(HID * HID + 255) / 256, 256, 0, stream>>>(W2, W2T, HID);

  k_count<<<(E + 1023) / 1024, 256, 0, stream>>>(dst, cnt, pos, E);
  int nch = (N + 1023) >> 10;
  k_scan_partial<<<nch, 256, 0, stream>>>(cnt, partials, N);
  k_scan_combine<<<1, 128, 0, stream>>>(partials, rowptr, nch, N);
  k_scan_final<<<nch, 256, 0, stream>>>(cnt, partials, rowptr, N);
  k_dinv<<<(N + 255) / 256, 256, 0, stream>>>(cnt, dinv, N);

  // mega: gemm1 || scatter || pad-fill (7-slot role pattern: 2/4/1)
  const int Gg1 = (N + 127) / 128;
  const int Gsc = (E + 2047) / 2048;
  const int Gfp = (N + 255) / 256;
  int ngroups = (Gg1 + 1) / 2;
  if ((Gsc + 3) / 4 > ngroups) ngroups = (Gsc + 3) / 4;
  if (Gfp > ngroups) ngroups = Gfp;
  k_mega<<<ngroups * 7, 256, 0, stream>>>(x, W1T, dinv, H0, N,
                                          src, dst, pos, rowptr, srcs, E, cnt,
                                          Gg1, Gsc, Gfp);

  k_agg<<<(N + 3) / 4, 256, 0, stream>>>((const uint*)H0, srcs, rowptr, dinv, b1,
                                         (uint*)H1, N);
  k_gemm2<<<(N + 127) / 128, 256, 0, stream>>>(H1, W2T, dinv, H0, N);
  k_agg_final<<<(N + 3) / 4, 256, 0, stream>>>((const uint*)H0, srcs, rowptr, dinv, b2,
                                               Wc, bc, out, N);
}